// Round 5
// baseline (105.797 us; speedup 1.0000x reference)
//
#include <hip/hip_runtime.h>
#include <hip/hip_bf16.h>

// KAN layer, round 5: persistent-ish blocks with software-prefetched edges.
//  - grid 1024, EPB=4 edges/block; next edge's weights global->reg during
//    current edge's compute, reg->LDS conversion behind edge-boundary barriers.
//  - Per-mti fusion (layer1 -> WB -> layer2 -> epilogue) with wave-private
//    16-row Hs buffer (in-order per-wave DS pipe => no barrier/waitcnt needed).
//  - LDS ~27 KB, per-mti accumulators (8 f32x4 live).
// Swapped GEMM D[n][m] = W[n][k]*H[m][k]; XOR swizzle byte ^= (row&7)<<4.

#define D_EDGES 4096
#define EPB 4

typedef __attribute__((ext_vector_type(4))) float f32x4;
typedef __attribute__((ext_vector_type(8))) short bf16x8;

__device__ __forceinline__ unsigned pk2(float a, float b) {
    __hip_bfloat162 h = __float22bfloat162_rn(float2{a, b});
    return *reinterpret_cast<unsigned*>(&h);
}

union BFr { unsigned u[4]; bf16x8 v; };

__global__ __launch_bounds__(256, 3) void kan_mfma(
    const float* __restrict__ x,     // (256, 64)
    const float* __restrict__ w0g,   // (D, 64)
    const float* __restrict__ b0g,   // (D, 64)
    const float* __restrict__ w1g,   // (D, 64, 64)
    const float* __restrict__ b1g,   // (D, 64)
    const float* __restrict__ w2g,   // (D, 64, 64)
    const float* __restrict__ b2g,   // (D, 64)
    const float* __restrict__ woutg, // (64, 4096)
    float* __restrict__ outbuf,      // partial (D,256) or y (256,64)
    int atomic_mode)
{
    const int t = threadIdx.x;
    const int lane = t & 63, wv = t >> 6;
    const int d0 = blockIdx.x * EPB;

    __shared__ __align__(16) unsigned char W1s[64 * 128];   // 8 KB
    __shared__ __align__(16) unsigned char W2s[64 * 128];   // 8 KB
    __shared__ __align__(16) unsigned char Hs[4 * 16 * 128];// 8 KB (16 rows/wave)
    __shared__ __align__(16) float sx[256];
    __shared__ __align__(16) float sw0[64], sb0[64], sb1[64], sb2[64], swo[64];

    const int orow = t >> 2, q = t & 3;
    const unsigned wswz  = (unsigned)((orow & 7) << 4);
    const unsigned wbase = (unsigned)(orow * 128);

    float4 s1r[4], s2r[4];
    float xv = 0.f, w0r = 0.f, b0r = 0.f, b1r = 0.f, b2r = 0.f, wor = 0.f;

    auto load_edge = [&](int dd) {
        const float* s1 = w1g + (size_t)dd * 4096 + orow * 64 + q * 16;
        const float* s2 = w2g + (size_t)dd * 4096 + orow * 64 + q * 16;
        s1r[0] = ((const float4*)s1)[0]; s1r[1] = ((const float4*)s1)[1];
        s1r[2] = ((const float4*)s1)[2]; s1r[3] = ((const float4*)s1)[3];
        s2r[0] = ((const float4*)s2)[0]; s2r[1] = ((const float4*)s2)[1];
        s2r[2] = ((const float4*)s2)[2]; s2r[3] = ((const float4*)s2)[3];
        xv = x[t * 64 + (dd & 63)];
        if (t < 64) {
            w0r = w0g[(size_t)dd * 64 + t];
            b0r = b0g[(size_t)dd * 64 + t];
            b1r = b1g[(size_t)dd * 64 + t];
            b2r = b2g[(size_t)dd * 64 + t];
            wor = woutg[(size_t)(dd >> 6) * 4096 + (dd & 63) * 64 + t];
        }
    };

    auto store_edge = [&]() {
        uint4 u0 = { pk2(s1r[0].x, s1r[0].y), pk2(s1r[0].z, s1r[0].w),
                     pk2(s1r[1].x, s1r[1].y), pk2(s1r[1].z, s1r[1].w) };
        uint4 u1 = { pk2(s1r[2].x, s1r[2].y), pk2(s1r[2].z, s1r[2].w),
                     pk2(s1r[3].x, s1r[3].y), pk2(s1r[3].z, s1r[3].w) };
        *(uint4*)&W1s[wbase + ((unsigned)(q * 32)      ^ wswz)] = u0;
        *(uint4*)&W1s[wbase + ((unsigned)(q * 32 + 16) ^ wswz)] = u1;
        uint4 v0 = { pk2(s2r[0].x, s2r[0].y), pk2(s2r[0].z, s2r[0].w),
                     pk2(s2r[1].x, s2r[1].y), pk2(s2r[1].z, s2r[1].w) };
        uint4 v1 = { pk2(s2r[2].x, s2r[2].y), pk2(s2r[2].z, s2r[2].w),
                     pk2(s2r[3].x, s2r[3].y), pk2(s2r[3].z, s2r[3].w) };
        *(uint4*)&W2s[wbase + ((unsigned)(q * 32)      ^ wswz)] = v0;
        *(uint4*)&W2s[wbase + ((unsigned)(q * 32 + 16) ^ wswz)] = v1;
        sx[t] = xv;
        if (t < 64) {
            sw0[t] = w0r; sb0[t] = b0r; sb1[t] = b1r; sb2[t] = b2r; swo[t] = wor;
        }
    };

    // prologue: stage edge d0
    load_edge(d0);
    store_edge();
    __syncthreads();

    const int arow = lane & 15;
    const int kb   = (lane >> 4) * 16;     // byte offset of this lane's 8 k-elems
    const int g8   = (lane >> 4) * 8;      // element offset
    const unsigned lswz = (unsigned)((lane & 7) << 4);
    const int r0 = (lane >> 4) * 4;
    const unsigned hbase = (unsigned)(wv * 2048 + arow * 128);
    const unsigned hswz  = (unsigned)((arow & 7) << 4);
    const f32x4 zero4 = { 0.f, 0.f, 0.f, 0.f };

    for (int e = 0; e < EPB; ++e) {
        const int d = d0 + e;
        const int o = d >> 6;

        // prefetch next edge's weights into registers (lands during compute)
        if (e + 1 < EPB) load_edge(d + 1);

        // ---- A-fragments for both layers (per edge) ----
        bf16x8 wf1[4][2], wf2[4][2];
#pragma unroll
        for (int nt = 0; nt < 4; ++nt)
#pragma unroll
            for (int ks = 0; ks < 2; ++ks) {
                wf1[nt][ks] = *(const bf16x8*)&W1s[(nt * 16 + arow) * 128 +
                                ((unsigned)(ks * 64 + kb) ^ lswz)];
                wf2[nt][ks] = *(const bf16x8*)&W2s[(nt * 16 + arow) * 128 +
                                ((unsigned)(ks * 64 + kb) ^ lswz)];
            }

        // ---- w0/b0 slices for this lane's k-positions ----
        float4 w0v[2][2], b0v[2][2];
#pragma unroll
        for (int ks = 0; ks < 2; ++ks) {
            const int k0 = ks * 32 + g8;
            w0v[ks][0] = *(const float4*)&sw0[k0];
            w0v[ks][1] = *(const float4*)&sw0[k0 + 4];
            b0v[ks][0] = *(const float4*)&sb0[k0];
            b0v[ks][1] = *(const float4*)&sb0[k0 + 4];
        }

#pragma unroll
        for (int mti = 0; mti < 4; ++mti) {
            const float xm = sx[wv * 64 + mti * 16 + arow];

            // ---- layer 1: B-frag in registers, MFMA ----
            f32x4 a1[4] = { zero4, zero4, zero4, zero4 };
#pragma unroll
            for (int ks = 0; ks < 2; ++ks) {
                float4 wa = w0v[ks][0], wb = w0v[ks][1];
                float4 ba = b0v[ks][0], bb = b0v[ks][1];
                float v0 = fmaxf(fmaf(xm, wa.x, ba.x), 0.f);
                float v1 = fmaxf(fmaf(xm, wa.y, ba.y), 0.f);
                float v2 = fmaxf(fmaf(xm, wa.z, ba.z), 0.f);
                float v3 = fmaxf(fmaf(xm, wa.w, ba.w), 0.f);
                float v4 = fmaxf(fmaf(xm, wb.x, bb.x), 0.f);
                float v5 = fmaxf(fmaf(xm, wb.y, bb.y), 0.f);
                float v6 = fmaxf(fmaf(xm, wb.z, bb.z), 0.f);
                float v7 = fmaxf(fmaf(xm, wb.w, bb.w), 0.f);
                BFr bh;
                bh.u[0] = pk2(v0, v1); bh.u[1] = pk2(v2, v3);
                bh.u[2] = pk2(v4, v5); bh.u[3] = pk2(v6, v7);
#pragma unroll
                for (int nt = 0; nt < 4; ++nt)
                    a1[nt] = __builtin_amdgcn_mfma_f32_16x16x32_bf16(
                        wf1[nt][ks], bh.v, a1[nt], 0, 0, 0);
            }

            // ---- H1 = relu(a1 + b1) -> wave-private 16-row LDS buffer ----
#pragma unroll
            for (int nt = 0; nt < 4; ++nt) {
                float4 bv = *(const float4*)&sb1[nt * 16 + r0];
                float v0 = fmaxf(a1[nt][0] + bv.x, 0.f);
                float v1 = fmaxf(a1[nt][1] + bv.y, 0.f);
                float v2 = fmaxf(a1[nt][2] + bv.z, 0.f);
                float v3 = fmaxf(a1[nt][3] + bv.w, 0.f);
                uint2 hp = { pk2(v0, v1), pk2(v2, v3) };
                *(uint2*)&Hs[hbase + ((unsigned)(2 * (nt * 16 + r0)) ^ hswz)] = hp;
            }
            // same-wave DS pipe is in-order: reads below see the writes above.

            // ---- layer 2 ----
            f32x4 a2[4] = { zero4, zero4, zero4, zero4 };
#pragma unroll
            for (int ks = 0; ks < 2; ++ks) {
                bf16x8 bh2 = *(const bf16x8*)&Hs[hbase + ((unsigned)(ks * 64 + kb) ^ hswz)];
#pragma unroll
                for (int nt = 0; nt < 4; ++nt)
                    a2[nt] = __builtin_amdgcn_mfma_f32_16x16x32_bf16(
                        wf2[nt][ks], bh2, a2[nt], 0, 0, 0);
            }

            // ---- epilogue: p = sum_n relu(a2 + b2[n]) * swo[n] ----
            float p = 0.f;
#pragma unroll
            for (int nt = 0; nt < 4; ++nt) {
                float4 bv = *(const float4*)&sb2[nt * 16 + r0];
                float4 wo = *(const float4*)&swo[nt * 16 + r0];
                p = fmaf(fmaxf(a2[nt][0] + bv.x, 0.f), wo.x, p);
                p = fmaf(fmaxf(a2[nt][1] + bv.y, 0.f), wo.y, p);
                p = fmaf(fmaxf(a2[nt][2] + bv.z, 0.f), wo.z, p);
                p = fmaf(fmaxf(a2[nt][3] + bv.w, 0.f), wo.w, p);
            }
            p += __shfl_xor(p, 16);
            p += __shfl_xor(p, 32);
            const int b = wv * 64 + mti * 16 + arow;
            if (lane < 16) {
                if (atomic_mode) atomicAdd(&outbuf[b * 64 + o], p);
                else             outbuf[(size_t)d * 256 + b] = p;
            }
        }

        // edge boundary: publish prefetched weights to LDS
        if (e + 1 < EPB) {
            __syncthreads();     // all waves done reading this edge's LDS
            store_edge();
            __syncthreads();     // LDS ready for next edge
        }
    }
}

// Deterministic reduction over ii: y[b,o] = bout[o] + sum_ii partial[(o*64+ii)*256 + b]
__global__ __launch_bounds__(256) void kan_reduce(
    const float* __restrict__ partial,
    const float* __restrict__ bout,
    float* __restrict__ y)
{
    const int o = blockIdx.x;    // 64
    const int b = threadIdx.x;   // 256
    float acc = bout[o];
    const float* p = partial + (size_t)o * (64 * 256) + b;
#pragma unroll
    for (int i = 0; i < 64; ++i)
        acc += p[i * 256];
    y[b * 64 + o] = acc;
}

__global__ __launch_bounds__(256) void kan_init_out(const float* __restrict__ bout,
                                                    float* __restrict__ y)
{
    const int idx = blockIdx.x * 256 + threadIdx.x;
    y[idx] = bout[idx & 63];
}

extern "C" void kernel_launch(void* const* d_in, const int* in_sizes, int n_in,
                              void* d_out, int out_size, void* d_ws, size_t ws_size,
                              hipStream_t stream) {
    const float* x    = (const float*)d_in[0];
    const float* w0   = (const float*)d_in[1];
    const float* b0   = (const float*)d_in[2];
    const float* w1   = (const float*)d_in[3];
    const float* b1   = (const float*)d_in[4];
    const float* w2   = (const float*)d_in[5];
    const float* b2   = (const float*)d_in[6];
    const float* wout = (const float*)d_in[7];
    const float* bout = (const float*)d_in[8];
    float* y = (float*)d_out;

    const size_t partial_bytes = (size_t)D_EDGES * 256 * sizeof(float); // 4 MB
    const int nblk = D_EDGES / EPB;  // 1024

    if (ws_size >= partial_bytes) {
        float* partial = (float*)d_ws;
        kan_mfma<<<nblk, 256, 0, stream>>>(x, w0, b0, w1, b1, w2, b2, wout, partial, 0);
        kan_reduce<<<64, 256, 0, stream>>>(partial, bout, y);
    } else {
        kan_init_out<<<64, 256, 0, stream>>>(bout, y);
        kan_mfma<<<nblk, 256, 0, stream>>>(x, w0, b0, w1, b1, w2, b2, wout, y, 1);
    }
}

// Round 6
// 42.667 us; speedup vs baseline: 2.4796x; 2.4796x over previous
//
#include <hip/hip_runtime.h>
#include <hip/hip_bf16.h>

// KAN layer, round 6: occupancy-focused.
//  - 1 edge/block, 4096 blocks. Round-4 staging (no lambdas, no prefetch regs).
//  - Round-5 per-mti fused inner loop (layer1->WB->layer2->epilogue), wave-private
//    16-row Hs => LDS ~27 KB => up to 6 blocks/CU.
//  - wf2 fragments loaded inside the mti loop (lower live VGPR); bounds (256,4).
// Swapped GEMM D[n][m] = W[n][k]*H[m][k]; XOR swizzle byte ^= (row&7)<<4.

#define D_EDGES 4096

typedef __attribute__((ext_vector_type(4))) float f32x4;
typedef __attribute__((ext_vector_type(8))) short bf16x8;

__device__ __forceinline__ unsigned pk2(float a, float b) {
    __hip_bfloat162 h = __float22bfloat162_rn(float2{a, b});
    return *reinterpret_cast<unsigned*>(&h);
}

union BFr { unsigned u[4]; bf16x8 v; };

__global__ __launch_bounds__(256, 4) void kan_mfma(
    const float* __restrict__ x,     // (256, 64)
    const float* __restrict__ w0g,   // (D, 64)
    const float* __restrict__ b0g,   // (D, 64)
    const float* __restrict__ w1g,   // (D, 64, 64)
    const float* __restrict__ b1g,   // (D, 64)
    const float* __restrict__ w2g,   // (D, 64, 64)
    const float* __restrict__ b2g,   // (D, 64)
    const float* __restrict__ woutg, // (64, 4096)
    float* __restrict__ outbuf,      // partial (D,256) or y (256,64)
    int atomic_mode)
{
    const int d = blockIdx.x, o = d >> 6, ii = d & 63;
    const int t = threadIdx.x;
    const int lane = t & 63, wv = t >> 6;

    __shared__ __align__(16) unsigned char W1s[64 * 128];    // 8 KB
    __shared__ __align__(16) unsigned char W2s[64 * 128];    // 8 KB
    __shared__ __align__(16) unsigned char Hs[4 * 16 * 128]; // 8 KB, 16 rows/wave
    __shared__ __align__(16) float sx[256];
    __shared__ __align__(16) float sw0[64], sb0[64], sb1[64], sb2[64], swo[64];

    // ---- stage W1, W2 -> bf16, swizzled (16 elems / thread / matrix) ----
    {
        const int orow = t >> 2, q = t & 3;
        const unsigned swz  = (unsigned)((orow & 7) << 4);
        const unsigned base = (unsigned)(orow * 128);
        const float* s1 = w1g + (size_t)d * 4096 + orow * 64 + q * 16;
        const float* s2 = w2g + (size_t)d * 4096 + orow * 64 + q * 16;

        float4 a0 = ((const float4*)s1)[0], a1 = ((const float4*)s1)[1];
        float4 a2 = ((const float4*)s1)[2], a3 = ((const float4*)s1)[3];
        uint4 u0 = { pk2(a0.x, a0.y), pk2(a0.z, a0.w), pk2(a1.x, a1.y), pk2(a1.z, a1.w) };
        uint4 u1 = { pk2(a2.x, a2.y), pk2(a2.z, a2.w), pk2(a3.x, a3.y), pk2(a3.z, a3.w) };
        *(uint4*)&W1s[base + ((unsigned)(q * 32)      ^ swz)] = u0;
        *(uint4*)&W1s[base + ((unsigned)(q * 32 + 16) ^ swz)] = u1;

        a0 = ((const float4*)s2)[0]; a1 = ((const float4*)s2)[1];
        a2 = ((const float4*)s2)[2]; a3 = ((const float4*)s2)[3];
        uint4 v0 = { pk2(a0.x, a0.y), pk2(a0.z, a0.w), pk2(a1.x, a1.y), pk2(a1.z, a1.w) };
        uint4 v1 = { pk2(a2.x, a2.y), pk2(a2.z, a2.w), pk2(a3.x, a3.y), pk2(a3.z, a3.w) };
        *(uint4*)&W2s[base + ((unsigned)(q * 32)      ^ swz)] = v0;
        *(uint4*)&W2s[base + ((unsigned)(q * 32 + 16) ^ swz)] = v1;
    }
    sx[t] = x[t * 64 + ii];
    if (t < 64) {
        sw0[t] = w0g[(size_t)d * 64 + t];
        sb0[t] = b0g[(size_t)d * 64 + t];
        sb1[t] = b1g[(size_t)d * 64 + t];
        sb2[t] = b2g[(size_t)d * 64 + t];
        swo[t] = woutg[(size_t)o * 4096 + ii * 64 + t];
    }
    __syncthreads();   // the only block-wide barrier

    const int arow = lane & 15;
    const int kb   = (lane >> 4) * 16;     // byte offset of this lane's 8 k-elems
    const int g8   = (lane >> 4) * 8;      // element offset
    const unsigned lswz = (unsigned)((lane & 7) << 4);
    const int r0 = (lane >> 4) * 4;
    const unsigned hbase = (unsigned)(wv * 2048 + arow * 128);
    const unsigned hswz  = (unsigned)((arow & 7) << 4);
    const f32x4 zero4 = { 0.f, 0.f, 0.f, 0.f };

    // ---- A-fragments for layer 1 (held in regs; reused all 4 m-tiles) ----
    bf16x8 wf1[4][2];
#pragma unroll
    for (int nt = 0; nt < 4; ++nt)
#pragma unroll
        for (int ks = 0; ks < 2; ++ks)
            wf1[nt][ks] = *(const bf16x8*)&W1s[(nt * 16 + arow) * 128 +
                            ((unsigned)(ks * 64 + kb) ^ lswz)];

    // ---- w0/b0 slices for this lane's k-positions ----
    float4 w0v[2][2], b0v[2][2];
#pragma unroll
    for (int ks = 0; ks < 2; ++ks) {
        const int k0 = ks * 32 + g8;
        w0v[ks][0] = *(const float4*)&sw0[k0];
        w0v[ks][1] = *(const float4*)&sw0[k0 + 4];
        b0v[ks][0] = *(const float4*)&sb0[k0];
        b0v[ks][1] = *(const float4*)&sb0[k0 + 4];
    }

#pragma unroll
    for (int mti = 0; mti < 4; ++mti) {
        const float xm = sx[wv * 64 + mti * 16 + arow];

        // ---- layer 1: B-frag in registers, MFMA ----
        f32x4 a1[4] = { zero4, zero4, zero4, zero4 };
#pragma unroll
        for (int ks = 0; ks < 2; ++ks) {
            float4 wa = w0v[ks][0], wb = w0v[ks][1];
            float4 ba = b0v[ks][0], bb = b0v[ks][1];
            float v0 = fmaxf(fmaf(xm, wa.x, ba.x), 0.f);
            float v1 = fmaxf(fmaf(xm, wa.y, ba.y), 0.f);
            float v2 = fmaxf(fmaf(xm, wa.z, ba.z), 0.f);
            float v3 = fmaxf(fmaf(xm, wa.w, ba.w), 0.f);
            float v4 = fmaxf(fmaf(xm, wb.x, bb.x), 0.f);
            float v5 = fmaxf(fmaf(xm, wb.y, bb.y), 0.f);
            float v6 = fmaxf(fmaf(xm, wb.z, bb.z), 0.f);
            float v7 = fmaxf(fmaf(xm, wb.w, bb.w), 0.f);
            BFr bh;
            bh.u[0] = pk2(v0, v1); bh.u[1] = pk2(v2, v3);
            bh.u[2] = pk2(v4, v5); bh.u[3] = pk2(v6, v7);
#pragma unroll
            for (int nt = 0; nt < 4; ++nt)
                a1[nt] = __builtin_amdgcn_mfma_f32_16x16x32_bf16(
                    wf1[nt][ks], bh.v, a1[nt], 0, 0, 0);
        }

        // ---- H1 = relu(a1 + b1) -> wave-private 16-row LDS buffer ----
#pragma unroll
        for (int nt = 0; nt < 4; ++nt) {
            float4 bv = *(const float4*)&sb1[nt * 16 + r0];
            float v0 = fmaxf(a1[nt][0] + bv.x, 0.f);
            float v1 = fmaxf(a1[nt][1] + bv.y, 0.f);
            float v2 = fmaxf(a1[nt][2] + bv.z, 0.f);
            float v3 = fmaxf(a1[nt][3] + bv.w, 0.f);
            uint2 hp = { pk2(v0, v1), pk2(v2, v3) };
            *(uint2*)&Hs[hbase + ((unsigned)(2 * (nt * 16 + r0)) ^ hswz)] = hp;
        }
        // same-wave DS pipe; compiler inserts the lgkmcnt dependency waits.

        // ---- layer 2: wf2 fragments loaded here (not held across mti) ----
        f32x4 a2[4] = { zero4, zero4, zero4, zero4 };
#pragma unroll
        for (int ks = 0; ks < 2; ++ks) {
            bf16x8 bh2 = *(const bf16x8*)&Hs[hbase + ((unsigned)(ks * 64 + kb) ^ hswz)];
#pragma unroll
            for (int nt = 0; nt < 4; ++nt) {
                bf16x8 wf2f = *(const bf16x8*)&W2s[(nt * 16 + arow) * 128 +
                                ((unsigned)(ks * 64 + kb) ^ lswz)];
                a2[nt] = __builtin_amdgcn_mfma_f32_16x16x32_bf16(
                    wf2f, bh2, a2[nt], 0, 0, 0);
            }
        }

        // ---- epilogue: p = sum_n relu(a2 + b2[n]) * swo[n] ----
        float p = 0.f;
#pragma unroll
        for (int nt = 0; nt < 4; ++nt) {
            float4 bv = *(const float4*)&sb2[nt * 16 + r0];
            float4 wo = *(const float4*)&swo[nt * 16 + r0];
            p = fmaf(fmaxf(a2[nt][0] + bv.x, 0.f), wo.x, p);
            p = fmaf(fmaxf(a2[nt][1] + bv.y, 0.f), wo.y, p);
            p = fmaf(fmaxf(a2[nt][2] + bv.z, 0.f), wo.z, p);
            p = fmaf(fmaxf(a2[nt][3] + bv.w, 0.f), wo.w, p);
        }
        p += __shfl_xor(p, 16);
        p += __shfl_xor(p, 32);
        const int b = wv * 64 + mti * 16 + arow;
        if (lane < 16) {
            if (atomic_mode) atomicAdd(&outbuf[b * 64 + o], p);
            else             outbuf[(size_t)d * 256 + b] = p;
        }
    }
}

// Deterministic reduction over ii: y[b,o] = bout[o] + sum_ii partial[(o*64+ii)*256 + b]
__global__ __launch_bounds__(256) void kan_reduce(
    const float* __restrict__ partial,
    const float* __restrict__ bout,
    float* __restrict__ y)
{
    const int o = blockIdx.x;    // 64
    const int b = threadIdx.x;   // 256
    float acc = bout[o];
    const float* p = partial + (size_t)o * (64 * 256) + b;
#pragma unroll
    for (int i = 0; i < 64; ++i)
        acc += p[i * 256];
    y[b * 64 + o] = acc;
}

__global__ __launch_bounds__(256) void kan_init_out(const float* __restrict__ bout,
                                                    float* __restrict__ y)
{
    const int idx = blockIdx.x * 256 + threadIdx.x;
    y[idx] = bout[idx & 63];
}

extern "C" void kernel_launch(void* const* d_in, const int* in_sizes, int n_in,
                              void* d_out, int out_size, void* d_ws, size_t ws_size,
                              hipStream_t stream) {
    const float* x    = (const float*)d_in[0];
    const float* w0   = (const float*)d_in[1];
    const float* b0   = (const float*)d_in[2];
    const float* w1   = (const float*)d_in[3];
    const float* b1   = (const float*)d_in[4];
    const float* w2   = (const float*)d_in[5];
    const float* b2   = (const float*)d_in[6];
    const float* wout = (const float*)d_in[7];
    const float* bout = (const float*)d_in[8];
    float* y = (float*)d_out;

    const size_t partial_bytes = (size_t)D_EDGES * 256 * sizeof(float); // 4 MB

    if (ws_size >= partial_bytes) {
        float* partial = (float*)d_ws;
        kan_mfma<<<D_EDGES, 256, 0, stream>>>(x, w0, b0, w1, b1, w2, b2, wout, partial, 0);
        kan_reduce<<<64, 256, 0, stream>>>(partial, bout, y);
    } else {
        kan_init_out<<<64, 256, 0, stream>>>(bout, y);
        kan_mfma<<<D_EDGES, 256, 0, stream>>>(x, w0, b0, w1, b1, w2, b2, wout, y, 1);
    }
}